// Round 7
// baseline (145.869 us; speedup 1.0000x reference)
//
#include <hip/hip_runtime.h>
#include <hip/hip_bf16.h>

#define N_NODES 30000
#define T_TYPES 4
#define F_DIM   128
#define H_HEADS 8

typedef __bf16 bf16x8 __attribute__((ext_vector_type(8)));
typedef __bf16 bf16x4 __attribute__((ext_vector_type(4)));
typedef float  floatx4 __attribute__((ext_vector_type(4)));

// ws layout:
//   [0,      64)      counts[4] (zeroed by hipMemsetAsync each launch)
//   [64,     480064)  reorder[4*N] int  (type t region at t*N)
//   [480256, 611328)  node_proj bf16  (4*128*128)
//   [611328, 1135616) edge_proj bf16  (16*128*128)
#define WS_REORDER 64
#define WS_NPB     480256
#define WS_EPB     611328

// 16-lane (row) sum via DPP on the VALU pipe — no LDS traffic.
template <int CTRL>
static __device__ __forceinline__ float dpp_add(float x) {
    int xi = __builtin_bit_cast(int, x);
    int yi = __builtin_amdgcn_update_dpp(xi, xi, CTRL, 0xF, 0xF, true);
    return x + __builtin_bit_cast(float, yi);
}
static __device__ __forceinline__ float sum16(float x) {
    x = dpp_add<0xB1>(x);    // xor 1
    x = dpp_add<0x4E>(x);    // xor 2
    x = dpp_add<0x141>(x);   // row_half_mirror
    x = dpp_add<0x140>(x);   // row_mirror
    return x;
}

// ---- kernel 0 (fused): blocks [0,320) convert tables; [320,438) bucket -----
__global__ __launch_bounds__(256) void prep_bucket_kernel(
    const float* __restrict__ node_proj, const float* __restrict__ edge_proj,
    __bf16* __restrict__ npb, __bf16* __restrict__ epb,
    const int* __restrict__ mask, int* __restrict__ counts, int* __restrict__ reorder)
{
    const int b = blockIdx.x;
    if (b < 320) {
        // ---- table fp32 -> bf16 conversion ----
        int i = b * 256 + threadIdx.x;            // 0..81919, each converts 4 floats
        int base = i * 4;
        float4 v;
        __bf16* dst;
        if (base < T_TYPES * F_DIM * F_DIM) {
            v = ((const float4*)node_proj)[i];
            dst = npb + base;
        } else {
            int off = base - T_TYPES * F_DIM * F_DIM;
            v = ((const float4*)edge_proj)[off >> 2];
            dst = epb + off;
        }
        bf16x4 w = { (__bf16)v.x, (__bf16)v.y, (__bf16)v.z, (__bf16)v.w };
        *(bf16x4*)dst = w;
    } else {
        // ---- bucket nodes by type (wave-aggregated atomics) ----
        int n = (b - 320) * 256 + threadIdx.x;
        int lane = threadIdx.x & 63;
        int t = (n < N_NODES) ? mask[n] : -1;
        #pragma unroll
        for (int tt = 0; tt < T_TYPES; ++tt) {
            unsigned long long bm = __ballot(t == tt);
            if (bm == 0ull) continue;             // wave-uniform
            int cnt = __popcll(bm);
            int leader = __ffsll((unsigned long long)bm) - 1;
            int base = 0;
            if (lane == leader) base = atomicAdd(&counts[tt], cnt);
            base = __shfl(base, leader);
            if (t == tt) {
                int prefix = __popcll(bm & ((1ull << lane) - 1ull));
                reorder[tt * N_NODES + base + prefix] = n;
            }
        }
    }
}

// ---------------- kernel 1: fused proj-GEMM + scores + head-softmax ----------
// OCCUPANCY VERSION: Aedge staged as two j-halves (j01 then restaged j23) so
// LDS ~31 KB; __launch_bounds__(512,8) caps VGPR at 64. 4 blocks/CU ->
// 1024 resident slots >= 941 blocks: the whole grid runs in ONE round and
// 32 waves/CU hide the JIT B-load latency (R0-style lean compute, 40 VGPR).
// Exact grid: block derives (t, start) from counts prefix.
__global__ __launch_bounds__(512, 8) void main_kernel(
    const float* __restrict__ feature, const float* __restrict__ edge_fea,
    const int* __restrict__ counts, const int* __restrict__ reorder,
    const __bf16* __restrict__ npb, const __bf16* __restrict__ epb,
    float* __restrict__ out)
{
    const int b = blockIdx.x;
    // ---- exact (t, start) from counts prefix over ceil(Nt/32) ----
    const int c0 = counts[0], c1 = counts[1], c2 = counts[2], c3 = counts[3];
    const int nb0 = (c0 + 31) >> 5, nb1 = (c1 + 31) >> 5, nb2 = (c2 + 31) >> 5, nb3 = (c3 + 31) >> 5;
    const int p1 = nb0, p2 = p1 + nb1, p3 = p2 + nb2, p4 = p3 + nb3;
    if (b >= p4) return;
    const int t = (b >= p1) + (b >= p2) + (b >= p3);
    const int pb = (t == 0) ? 0 : (t == 1) ? p1 : (t == 2) ? p2 : p3;
    const int Nt = (t == 0) ? c0 : (t == 1) ? c1 : (t == 2) ? c2 : c3;
    const int start = (b - pb) * 32;
    const int valid = min(32, Nt - start);

    // +8 bf16 row pad (16B): 272B stride -> (4r+c)%32 banks, 2-way only (free)
    __shared__ __bf16 Afeat[32][136];
    __shared__ __bf16 Aedge[2][32][136];        // two j-planes at a time
    __shared__ float  sc[32][4][H_HEADS + 1];
    __shared__ int    nidx[32];

    const int tid = threadIdx.x;
    if (tid < 32) {
        int s = (tid < valid) ? tid : (valid - 1);   // clamp-dup tail nodes
        nidx[tid] = reorder[t * N_NODES + start + s];
    }
    __syncthreads();

    // ---- stage A: feature rows + edge j=0,1 (coalesced float4 per row) ----
    const int colv = tid & 31;     // float4 index within a 128-float row
    const int rowg = tid >> 5;     // 16 rows in flight
    #pragma unroll
    for (int it = 0; it < 2; ++it) {             // 32 feature rows
        int row = it * 16 + rowg;
        float4 v = ((const float4*)(feature + (long)nidx[row] * F_DIM))[colv];
        bf16x4 w = { (__bf16)v.x, (__bf16)v.y, (__bf16)v.z, (__bf16)v.w };
        *(bf16x4*)(&Afeat[row][0] + colv * 4) = w;
    }
    #pragma unroll
    for (int it = 0; it < 4; ++it) {             // 64 edge rows (j = 0,1)
        int row = it * 16 + rowg;                // 0..63
        int j = row >> 5, r = row & 31;
        float4 v = ((const float4*)(edge_fea + ((long)nidx[r] * 4 + j) * F_DIM))[colv];
        bf16x4 w = { (__bf16)v.x, (__bf16)v.y, (__bf16)v.z, (__bf16)v.w };
        *(bf16x4*)(&Aedge[j][r][0] + colv * 4) = w;
    }
    __syncthreads();

    const int lane = tid & 63;
    const int wave = tid >> 6;                 // 0..7 == head
    const int ml   = lane & 15;
    const int quad = lane >> 4;
    const int g0   = wave * 16;

    // ---- node GEMM: accN[mt] = feature_tile @ node_proj[t]^T (16 g-cols) ----
    floatx4 accN[2] = {};
    {
        const __bf16* a0 = &Afeat[ml][quad * 8];
        const __bf16* a1 = &Afeat[16 + ml][quad * 8];
        const __bf16* b0 = npb + t * (F_DIM * F_DIM) + (g0 + ml) * F_DIM + quad * 8;
        #pragma unroll
        for (int k0 = 0; k0 < 128; k0 += 32) {
            bf16x8 A0 = *(const bf16x8*)(a0 + k0);
            bf16x8 A1 = *(const bf16x8*)(a1 + k0);
            bf16x8 B0 = *(const bf16x8*)(b0 + k0);
            accN[0] = __builtin_amdgcn_mfma_f32_16x16x32_bf16(A0, B0, accN[0], 0, 0, 0);
            accN[1] = __builtin_amdgcn_mfma_f32_16x16x32_bf16(A1, B0, accN[1], 0, 0, 0);
        }
    }

    // ---- edge GEMMs j=0,1 (plane j) + fused score reduction (DPP) ----
    #pragma unroll
    for (int j = 0; j < 2; ++j) {
        floatx4 accE[2] = {};
        const __bf16* a0 = &Aedge[j][ml][quad * 8];
        const __bf16* a1 = &Aedge[j][16 + ml][quad * 8];
        const __bf16* b0 = epb + (t * 4 + j) * (F_DIM * F_DIM) + (g0 + ml) * F_DIM + quad * 8;
        #pragma unroll
        for (int k0 = 0; k0 < 128; k0 += 32) {
            bf16x8 A0 = *(const bf16x8*)(a0 + k0);
            bf16x8 A1 = *(const bf16x8*)(a1 + k0);
            bf16x8 B0 = *(const bf16x8*)(b0 + k0);
            accE[0] = __builtin_amdgcn_mfma_f32_16x16x32_bf16(A0, B0, accE[0], 0, 0, 0);
            accE[1] = __builtin_amdgcn_mfma_f32_16x16x32_bf16(A1, B0, accE[1], 0, 0, 0);
        }
        #pragma unroll
        for (int mt = 0; mt < 2; ++mt) {
            floatx4 p = accN[mt] * accE[mt];
            p.x = sum16(p.x); p.y = sum16(p.y); p.z = sum16(p.z); p.w = sum16(p.w);
            if (ml == 0) {                       // one writer per 16-lane row
                int mb = mt * 16 + quad * 4;     // C/D row = quad*4+reg
                sc[mb + 0][j][wave] = p.x * 0.25f;
                sc[mb + 1][j][wave] = p.y * 0.25f;
                sc[mb + 2][j][wave] = p.z * 0.25f;
                sc[mb + 3][j][wave] = p.w * 0.25f;
            }
        }
    }
    __syncthreads();                             // all waves done reading j01 planes

    // ---- restage edge j=2,3 into the same two planes ----
    #pragma unroll
    for (int it = 0; it < 4; ++it) {             // 64 edge rows (j = 2,3)
        int row = it * 16 + rowg;                // 0..63
        int j = row >> 5, r = row & 31;
        float4 v = ((const float4*)(edge_fea + ((long)nidx[r] * 4 + 2 + j) * F_DIM))[colv];
        bf16x4 w = { (__bf16)v.x, (__bf16)v.y, (__bf16)v.z, (__bf16)v.w };
        *(bf16x4*)(&Aedge[j][r][0] + colv * 4) = w;
    }
    __syncthreads();

    // ---- edge GEMMs j=2,3 (plane j-2) + fused score reduction (DPP) ----
    #pragma unroll
    for (int j = 2; j < 4; ++j) {
        floatx4 accE[2] = {};
        const __bf16* a0 = &Aedge[j - 2][ml][quad * 8];
        const __bf16* a1 = &Aedge[j - 2][16 + ml][quad * 8];
        const __bf16* b0 = epb + (t * 4 + j) * (F_DIM * F_DIM) + (g0 + ml) * F_DIM + quad * 8;
        #pragma unroll
        for (int k0 = 0; k0 < 128; k0 += 32) {
            bf16x8 A0 = *(const bf16x8*)(a0 + k0);
            bf16x8 A1 = *(const bf16x8*)(a1 + k0);
            bf16x8 B0 = *(const bf16x8*)(b0 + k0);
            accE[0] = __builtin_amdgcn_mfma_f32_16x16x32_bf16(A0, B0, accE[0], 0, 0, 0);
            accE[1] = __builtin_amdgcn_mfma_f32_16x16x32_bf16(A1, B0, accE[1], 0, 0, 0);
        }
        #pragma unroll
        for (int mt = 0; mt < 2; ++mt) {
            floatx4 p = accN[mt] * accE[mt];
            p.x = sum16(p.x); p.y = sum16(p.y); p.z = sum16(p.z); p.w = sum16(p.w);
            if (ml == 0) {
                int mb = mt * 16 + quad * 4;
                sc[mb + 0][j][wave] = p.x * 0.25f;
                sc[mb + 1][j][wave] = p.y * 0.25f;
                sc[mb + 2][j][wave] = p.z * 0.25f;
                sc[mb + 3][j][wave] = p.w * 0.25f;
            }
        }
    }
    __syncthreads();

    // ---- softmax over heads (axis=1 of [N,H,1,T]) -> out[n][j][h] ----
    if (tid < 128) {
        int node = tid >> 2, j = tid & 3;
        if (node < valid) {
            float v[8], m = -1e30f;
            #pragma unroll
            for (int h = 0; h < 8; ++h) { v[h] = sc[node][j][h]; m = fmaxf(m, v[h]); }
            float s = 0.f;
            #pragma unroll
            for (int h = 0; h < 8; ++h) { v[h] = __expf(v[h] - m); s += v[h]; }
            float r = 1.0f / s;
            float* o = out + (long)nidx[node] * (T_TYPES * H_HEADS) + j * H_HEADS;
            float4 o0 = { v[0] * r, v[1] * r, v[2] * r, v[3] * r };
            float4 o1 = { v[4] * r, v[5] * r, v[6] * r, v[7] * r };
            ((float4*)o)[0] = o0;
            ((float4*)o)[1] = o1;
        }
    }
}

extern "C" void kernel_launch(void* const* d_in, const int* in_sizes, int n_in,
                              void* d_out, int out_size, void* d_ws, size_t ws_size,
                              hipStream_t stream) {
    const float* feature   = (const float*)d_in[0];
    const float* edge_fea  = (const float*)d_in[1];
    const int*   mask      = (const int*)d_in[2];
    const float* node_proj = (const float*)d_in[3];
    const float* edge_proj = (const float*)d_in[4];
    float* out = (float*)d_out;

    char* ws = (char*)d_ws;
    int*    counts  = (int*)ws;
    int*    reorder = (int*)(ws + WS_REORDER);
    __bf16* npb     = (__bf16*)(ws + WS_NPB);
    __bf16* epb     = (__bf16*)(ws + WS_EPB);

    hipMemsetAsync(counts, 0, T_TYPES * sizeof(int), stream);
    int prep_blocks = 320;                                  // 81920 convert threads
    int bucket_blocks = (N_NODES + 255) / 256;              // 118
    prep_bucket_kernel<<<prep_blocks + bucket_blocks, 256, 0, stream>>>(
        node_proj, edge_proj, npb, epb, mask, counts, reorder);
    int nblk = (N_NODES + 31) / 32 + T_TYPES - 1;           // 941: exact-grid bound
    main_kernel<<<nblk, 512, 0, stream>>>(feature, edge_fea, counts, reorder, npb, epb, out);
}

// Round 10
// 143.670 us; speedup vs baseline: 1.0153x; 1.0153x over previous
//
#include <hip/hip_runtime.h>
#include <hip/hip_bf16.h>

#define N_NODES 30000
#define T_TYPES 4
#define F_DIM   128
#define H_HEADS 8

typedef __bf16 bf16x8 __attribute__((ext_vector_type(8)));
typedef __bf16 bf16x4 __attribute__((ext_vector_type(4)));
typedef float  floatx4 __attribute__((ext_vector_type(4)));

// ws layout:
//   [0,      64)      counts[4] (zeroed by hipMemsetAsync each launch)
//   [64,     480064)  reorder[4*N] int  (type t region at t*N)
//   [480256, 611328)  node_proj bf16  (4*128*128)
//   [611328, 1135616) edge_proj bf16  (16*128*128)
#define WS_REORDER 64
#define WS_NPB     480256
#define WS_EPB     611328

// 16-lane (row) sum via DPP on the VALU pipe — no LDS traffic.
template <int CTRL>
static __device__ __forceinline__ float dpp_add(float x) {
    int xi = __builtin_bit_cast(int, x);
    int yi = __builtin_amdgcn_update_dpp(xi, xi, CTRL, 0xF, 0xF, true);
    return x + __builtin_bit_cast(float, yi);
}
static __device__ __forceinline__ float sum16(float x) {
    x = dpp_add<0xB1>(x);    // xor 1
    x = dpp_add<0x4E>(x);    // xor 2
    x = dpp_add<0x141>(x);   // row_half_mirror
    x = dpp_add<0x140>(x);   // row_mirror
    return x;
}

// ---- kernel 0 (fused): blocks [0,320) convert tables; [320,438) bucket -----
__global__ __launch_bounds__(256) void prep_bucket_kernel(
    const float* __restrict__ node_proj, const float* __restrict__ edge_proj,
    __bf16* __restrict__ npb, __bf16* __restrict__ epb,
    const int* __restrict__ mask, int* __restrict__ counts, int* __restrict__ reorder)
{
    const int b = blockIdx.x;
    if (b < 320) {
        // ---- table fp32 -> bf16 conversion ----
        int i = b * 256 + threadIdx.x;            // 0..81919, each converts 4 floats
        int base = i * 4;
        float4 v;
        __bf16* dst;
        if (base < T_TYPES * F_DIM * F_DIM) {
            v = ((const float4*)node_proj)[i];
            dst = npb + base;
        } else {
            int off = base - T_TYPES * F_DIM * F_DIM;
            v = ((const float4*)edge_proj)[off >> 2];
            dst = epb + off;
        }
        bf16x4 w = { (__bf16)v.x, (__bf16)v.y, (__bf16)v.z, (__bf16)v.w };
        *(bf16x4*)dst = w;
    } else {
        // ---- bucket nodes by type (wave-aggregated atomics) ----
        int n = (b - 320) * 256 + threadIdx.x;
        int lane = threadIdx.x & 63;
        int t = (n < N_NODES) ? mask[n] : -1;
        #pragma unroll
        for (int tt = 0; tt < T_TYPES; ++tt) {
            unsigned long long bm = __ballot(t == tt);
            if (bm == 0ull) continue;             // wave-uniform
            int cnt = __popcll(bm);
            int leader = __ffsll((unsigned long long)bm) - 1;
            int base = 0;
            if (lane == leader) base = atomicAdd(&counts[tt], cnt);
            base = __shfl(base, leader);
            if (t == tt) {
                int prefix = __popcll(bm & ((1ull << lane) - 1ull));
                reorder[tt * N_NODES + base + prefix] = n;
            }
        }
    }
}

// ---------------- kernel 1: fused proj-GEMM + scores + head-softmax ----------
// Exact grid (941 blocks): block derives (t, start) from counts prefix.
// Block: 512 threads (8 waves), 32 nodes of one type, all 128 outputs.
// Wave w owns g-slice [16w, 16w+16) == head h=w exactly (d = lane&15).
// B fragments prefetched: node-B + edge-j0-B issued BEFORE the staging
// barrier (its vmcnt(0) drain absorbs the latency); edge-B for j+1 issued
// before j's MFMA cluster, pinned with sched_barrier(0).
__global__ __launch_bounds__(512, 6) void main_kernel(
    const float* __restrict__ feature, const float* __restrict__ edge_fea,
    const int* __restrict__ counts, const int* __restrict__ reorder,
    const __bf16* __restrict__ npb, const __bf16* __restrict__ epb,
    float* __restrict__ out)
{
    const int b = blockIdx.x;
    // ---- exact (t, start) from counts prefix over ceil(Nt/32) ----
    const int c0 = counts[0], c1 = counts[1], c2 = counts[2], c3 = counts[3];
    const int nb0 = (c0 + 31) >> 5, nb1 = (c1 + 31) >> 5, nb2 = (c2 + 31) >> 5, nb3 = (c3 + 31) >> 5;
    const int p1 = nb0, p2 = p1 + nb1, p3 = p2 + nb2, p4 = p3 + nb3;
    if (b >= p4) return;
    const int t = (b >= p1) + (b >= p2) + (b >= p3);
    const int pb = (t == 0) ? 0 : (t == 1) ? p1 : (t == 2) ? p2 : p3;
    const int Nt = (t == 0) ? c0 : (t == 1) ? c1 : (t == 2) ? c2 : c3;
    const int start = (b - pb) * 32;
    const int valid = min(32, Nt - start);

    // +8 bf16 row pad (16B): rows land 4 banks apart
    __shared__ __bf16 Afeat[32][136];
    __shared__ __bf16 Aedge[4][32][136];
    __shared__ float  sc[32][4][H_HEADS + 1];
    __shared__ int    nidx[32];

    const int tid = threadIdx.x;
    if (tid < 32) {
        int s = (tid < valid) ? tid : (valid - 1);   // clamp-dup tail nodes
        nidx[tid] = reorder[t * N_NODES + start + s];
    }
    __syncthreads();

    const int lane = tid & 63;
    const int wave = tid >> 6;                 // 0..7 == head
    const int ml   = lane & 15;
    const int quad = lane >> 4;
    const int g0   = wave * 16;

    // ---- stage A: fp32 global -> bf16 LDS (coalesced float4 per row) ----
    const int colv = tid & 31;     // float4 index within a 128-float row
    const int rowg = tid >> 5;     // 16 rows in flight
    #pragma unroll
    for (int it = 0; it < 2; ++it) {             // 32 feature rows
        int row = it * 16 + rowg;
        float4 v = ((const float4*)(feature + (long)nidx[row] * F_DIM))[colv];
        bf16x4 w = { (__bf16)v.x, (__bf16)v.y, (__bf16)v.z, (__bf16)v.w };
        *(bf16x4*)(&Afeat[row][0] + colv * 4) = w;
    }
    #pragma unroll
    for (int it = 0; it < 8; ++it) {             // 128 edge rows
        int row = it * 16 + rowg;                // 0..127
        int j = row >> 5, r = row & 31;
        float4 v = ((const float4*)(edge_fea + ((long)nidx[r] * 4 + j) * F_DIM))[colv];
        bf16x4 w = { (__bf16)v.x, (__bf16)v.y, (__bf16)v.z, (__bf16)v.w };
        *(bf16x4*)(&Aedge[j][r][0] + colv * 4) = w;
    }

    // ---- prefetch node-B + edge-j0-B BEFORE the barrier ----
    const __bf16* bn  = npb + t * (F_DIM * F_DIM) + (g0 + ml) * F_DIM + quad * 8;
    const __bf16* be  = epb + (t * 4) * (F_DIM * F_DIM) + (g0 + ml) * F_DIM + quad * 8;
    bf16x8 Bn0 = *(const bf16x8*)(bn +  0);
    bf16x8 Bn1 = *(const bf16x8*)(bn + 32);
    bf16x8 Bn2 = *(const bf16x8*)(bn + 64);
    bf16x8 Bn3 = *(const bf16x8*)(bn + 96);
    bf16x8 Bc0 = *(const bf16x8*)(be +  0);
    bf16x8 Bc1 = *(const bf16x8*)(be + 32);
    bf16x8 Bc2 = *(const bf16x8*)(be + 64);
    bf16x8 Bc3 = *(const bf16x8*)(be + 96);
    __syncthreads();                             // vmcnt(0) drain covers B loads

    // ---- node GEMM: accN[mt] = feature_tile @ node_proj[t]^T (16 g-cols) ----
    floatx4 accN0 = {0.f, 0.f, 0.f, 0.f};
    floatx4 accN1 = {0.f, 0.f, 0.f, 0.f};
    {
        const __bf16* a0 = &Afeat[ml][quad * 8];
        const __bf16* a1 = &Afeat[16 + ml][quad * 8];
        bf16x8 A00 = *(const bf16x8*)(a0 +  0);
        bf16x8 A10 = *(const bf16x8*)(a1 +  0);
        bf16x8 A01 = *(const bf16x8*)(a0 + 32);
        bf16x8 A11 = *(const bf16x8*)(a1 + 32);
        bf16x8 A02 = *(const bf16x8*)(a0 + 64);
        bf16x8 A12 = *(const bf16x8*)(a1 + 64);
        bf16x8 A03 = *(const bf16x8*)(a0 + 96);
        bf16x8 A13 = *(const bf16x8*)(a1 + 96);
        accN0 = __builtin_amdgcn_mfma_f32_16x16x32_bf16(A00, Bn0, accN0, 0, 0, 0);
        accN1 = __builtin_amdgcn_mfma_f32_16x16x32_bf16(A10, Bn0, accN1, 0, 0, 0);
        accN0 = __builtin_amdgcn_mfma_f32_16x16x32_bf16(A01, Bn1, accN0, 0, 0, 0);
        accN1 = __builtin_amdgcn_mfma_f32_16x16x32_bf16(A11, Bn1, accN1, 0, 0, 0);
        accN0 = __builtin_amdgcn_mfma_f32_16x16x32_bf16(A02, Bn2, accN0, 0, 0, 0);
        accN1 = __builtin_amdgcn_mfma_f32_16x16x32_bf16(A12, Bn2, accN1, 0, 0, 0);
        accN0 = __builtin_amdgcn_mfma_f32_16x16x32_bf16(A03, Bn3, accN0, 0, 0, 0);
        accN1 = __builtin_amdgcn_mfma_f32_16x16x32_bf16(A13, Bn3, accN1, 0, 0, 0);
    }

    // ---- edge GEMMs, 2-deep B pipeline + fused score reduction (DPP) ----
    #pragma unroll
    for (int j = 0; j < 4; ++j) {
        bf16x8 Bf0, Bf1, Bf2, Bf3;               // next j's B, issued first
        if (j < 3) {
            const __bf16* bf = epb + (t * 4 + j + 1) * (F_DIM * F_DIM) + (g0 + ml) * F_DIM + quad * 8;
            Bf0 = *(const bf16x8*)(bf +  0);
            Bf1 = *(const bf16x8*)(bf + 32);
            Bf2 = *(const bf16x8*)(bf + 64);
            Bf3 = *(const bf16x8*)(bf + 96);
        }
        __builtin_amdgcn_sched_barrier(0);       // pin prefetch above MFMA cluster

        const __bf16* a0 = &Aedge[j][ml][quad * 8];
        const __bf16* a1 = &Aedge[j][16 + ml][quad * 8];
        bf16x8 E00 = *(const bf16x8*)(a0 +  0);
        bf16x8 E10 = *(const bf16x8*)(a1 +  0);
        bf16x8 E01 = *(const bf16x8*)(a0 + 32);
        bf16x8 E11 = *(const bf16x8*)(a1 + 32);
        bf16x8 E02 = *(const bf16x8*)(a0 + 64);
        bf16x8 E12 = *(const bf16x8*)(a1 + 64);
        bf16x8 E03 = *(const bf16x8*)(a0 + 96);
        bf16x8 E13 = *(const bf16x8*)(a1 + 96);
        floatx4 accE0 = {0.f, 0.f, 0.f, 0.f};
        floatx4 accE1 = {0.f, 0.f, 0.f, 0.f};
        accE0 = __builtin_amdgcn_mfma_f32_16x16x32_bf16(E00, Bc0, accE0, 0, 0, 0);
        accE1 = __builtin_amdgcn_mfma_f32_16x16x32_bf16(E10, Bc0, accE1, 0, 0, 0);
        accE0 = __builtin_amdgcn_mfma_f32_16x16x32_bf16(E01, Bc1, accE0, 0, 0, 0);
        accE1 = __builtin_amdgcn_mfma_f32_16x16x32_bf16(E11, Bc1, accE1, 0, 0, 0);
        accE0 = __builtin_amdgcn_mfma_f32_16x16x32_bf16(E02, Bc2, accE0, 0, 0, 0);
        accE1 = __builtin_amdgcn_mfma_f32_16x16x32_bf16(E12, Bc2, accE1, 0, 0, 0);
        accE0 = __builtin_amdgcn_mfma_f32_16x16x32_bf16(E03, Bc3, accE0, 0, 0, 0);
        accE1 = __builtin_amdgcn_mfma_f32_16x16x32_bf16(E13, Bc3, accE1, 0, 0, 0);

        // score[m][h=wave][j] = (1/4) * sum_d node_p*edge_p ; d == lane&15
        {
            floatx4 p = accN0 * accE0;
            p.x = sum16(p.x); p.y = sum16(p.y); p.z = sum16(p.z); p.w = sum16(p.w);
            if (ml == 0) {
                int mb = quad * 4;               // C/D row = quad*4+reg
                sc[mb + 0][j][wave] = p.x * 0.25f;
                sc[mb + 1][j][wave] = p.y * 0.25f;
                sc[mb + 2][j][wave] = p.z * 0.25f;
                sc[mb + 3][j][wave] = p.w * 0.25f;
            }
        }
        {
            floatx4 p = accN1 * accE1;
            p.x = sum16(p.x); p.y = sum16(p.y); p.z = sum16(p.z); p.w = sum16(p.w);
            if (ml == 0) {
                int mb = 16 + quad * 4;
                sc[mb + 0][j][wave] = p.x * 0.25f;
                sc[mb + 1][j][wave] = p.y * 0.25f;
                sc[mb + 2][j][wave] = p.z * 0.25f;
                sc[mb + 3][j][wave] = p.w * 0.25f;
            }
        }
        if (j < 3) { Bc0 = Bf0; Bc1 = Bf1; Bc2 = Bf2; Bc3 = Bf3; }
    }
    __syncthreads();

    // ---- softmax over heads (axis=1 of [N,H,1,T]) -> out[n][j][h] ----
    if (tid < 128) {
        int node = tid >> 2, j = tid & 3;
        if (node < valid) {
            float v[8], m = -1e30f;
            #pragma unroll
            for (int h = 0; h < 8; ++h) { v[h] = sc[node][j][h]; m = fmaxf(m, v[h]); }
            float s = 0.f;
            #pragma unroll
            for (int h = 0; h < 8; ++h) { v[h] = __expf(v[h] - m); s += v[h]; }
            float r = 1.0f / s;
            float* o = out + (long)nidx[node] * (T_TYPES * H_HEADS) + j * H_HEADS;
            float4 o0 = { v[0] * r, v[1] * r, v[2] * r, v[3] * r };
            float4 o1 = { v[4] * r, v[5] * r, v[6] * r, v[7] * r };
            ((float4*)o)[0] = o0;
            ((float4*)o)[1] = o1;
        }
    }
}

extern "C" void kernel_launch(void* const* d_in, const int* in_sizes, int n_in,
                              void* d_out, int out_size, void* d_ws, size_t ws_size,
                              hipStream_t stream) {
    const float* feature   = (const float*)d_in[0];
    const float* edge_fea  = (const float*)d_in[1];
    const int*   mask      = (const int*)d_in[2];
    const float* node_proj = (const float*)d_in[3];
    const float* edge_proj = (const float*)d_in[4];
    float* out = (float*)d_out;

    char* ws = (char*)d_ws;
    int*    counts  = (int*)ws;
    int*    reorder = (int*)(ws + WS_REORDER);
    __bf16* npb     = (__bf16*)(ws + WS_NPB);
    __bf16* epb     = (__bf16*)(ws + WS_EPB);

    hipMemsetAsync(counts, 0, T_TYPES * sizeof(int), stream);
    int prep_blocks = 320;                                  // 81920 convert threads
    int bucket_blocks = (N_NODES + 255) / 256;              // 118
    prep_bucket_kernel<<<prep_blocks + bucket_blocks, 256, 0, stream>>>(
        node_proj, edge_proj, npb, epb, mask, counts, reorder);
    int nblk = (N_NODES + 31) / 32 + T_TYPES - 1;           // 941: exact-grid bound
    main_kernel<<<nblk, 512, 0, stream>>>(feature, edge_fea, counts, reorder, npb, epb, out);
}